// Round 10
// baseline (885.511 us; speedup 1.0000x reference)
//
#include <hip/hip_runtime.h>
#include <hip/hip_bf16.h>
#include <math.h>

// Sizes from the reference
#define HDIM   256
#define NHEAD  4
#define LLAY   4
#define TLAY   4
#define KMAXC  10
#define MAXD   32
#define BATCH  64
#define MSUB   32
#define KNODE  32
#define SSUB   2048     // BATCH*MSUB
#define NNODE  65536    // SSUB*KNODE
#define NEDGE  131072
#define EPSPER 64       // NEDGE/SSUB
#define EDN    5

typedef unsigned short u16;   // raw bf16 bits (internal staging only)
typedef __attribute__((ext_vector_type(8))) short bf16x8;
typedef __attribute__((ext_vector_type(4))) float f32x4;

__device__ __forceinline__ float us2f(u16 u) {
    union { unsigned int i; float f; } x; x.i = ((unsigned int)u) << 16; return x.f;
}
__device__ __forceinline__ u16 f2us(float v) {
    union { float f; unsigned int i; } x; x.f = v;
    unsigned int u = x.i;
    u += 0x7fffu + ((u >> 16) & 1u);   // RNE
    return (u16)(u >> 16);
}
__device__ __forceinline__ float finite_or_zero(float v) {
    return (v == v && fabsf(v) <= 3.0e38f) ? v : 0.0f;
}
__device__ __forceinline__ void gll16(const u16* g, u16* l) {
    __builtin_amdgcn_global_load_lds(
        (const __attribute__((address_space(1))) unsigned int*)g,
        (__attribute__((address_space(3))) unsigned int*)l, 16, 0, 0);
}

// ---------------------------------------------------------------------------
// CSR precompute: per subgraph, edges sorted by local dst row.
__global__ __launch_bounds__(256) void k_csr(
    const int* __restrict__ src, const int* __restrict__ dst,
    const int* __restrict__ eid, u16* __restrict__ perm, u16* __restrict__ off)
{
    __shared__ int sL[4][64], dL[4][64], eL[4][64];
    int wave = threadIdx.x >> 6, lane = threadIdx.x & 63;
    int sgi = blockIdx.x * 4 + wave;
    sL[wave][lane] = src[sgi * 64 + lane] - sgi * KNODE;
    dL[wave][lane] = dst[sgi * 64 + lane] - sgi * KNODE;
    eL[wave][lane] = eid[sgi * 64 + lane];
    __syncthreads();
    if (lane < 32) {
        int cnt = 0;
        for (int e = 0; e < 64; ++e) cnt += (dL[wave][e] == lane) ? 1 : 0;
        int incl = cnt;
        #pragma unroll
        for (int d = 1; d < 32; d <<= 1) {
            int v = __shfl_up(incl, d, 64);
            if (lane >= d) incl += v;
        }
        int start = incl - cnt;
        off[sgi * 32 + lane] = (u16)start;
        int pos = start;
        for (int e = 0; e < 64; ++e) {
            if (dL[wave][e] == lane) {
                perm[sgi * 64 + pos] = (u16)((sL[wave][e] << 3) | eL[wave][e]);
                ++pos;
            }
        }
    }
}

// ---------------------------------------------------------------------------
// Weight transpose+convert: W (K x N f32, slice z) -> WT (N x K bf16).
__global__ __launch_bounds__(256) void k_wtrans(
    const float* __restrict__ W, u16* __restrict__ WT, int K, int N)
{
    __shared__ float til[32][33];
    int k0 = blockIdx.x * 32, n0 = blockIdx.y * 32, s = blockIdx.z;
    const float* Wb = W + (size_t)s * K * N;
    u16* Tb = WT + (size_t)s * N * K;
    int j = threadIdx.x & 31, i0 = threadIdx.x >> 5;
    #pragma unroll
    for (int it = 0; it < 4; ++it) {
        int i = i0 + it * 8;
        til[i][j] = Wb[(size_t)(k0 + i) * N + n0 + j];
    }
    __syncthreads();
    #pragma unroll
    for (int it = 0; it < 4; ++it) {
        int i = i0 + it * 8;
        Tb[(size_t)(n0 + i) * K + k0 + j] = f2us(til[j][i]);
    }
}

// ---------------------------------------------------------------------------
// Fully-fused GNN: h-init + ALL 4 layers + root-row extraction in ONE kernel.
// One block = 2 subgraphs = 64 rows, LDS-resident. launch_bounds(256,2):
// VGPR cap 256 fits wf[4][8]+acc (no scratch spill — R9's 81MB WRITE was spill).
__global__ __launch_bounds__(256, 2) void k_gnn4(
    const int* __restrict__ x_ids, const int* __restrict__ dist,
    const int* __restrict__ nodes, const float* __restrict__ lp,
    const float* __restrict__ atom_emb, const float* __restrict__ dist_emb,
    const float* __restrict__ logp_W, const float* __restrict__ logp_b,
    const u16* __restrict__ perm, const u16* __restrict__ off,
    const float* __restrict__ bond_emb, const float* __restrict__ eps_arr,
    const float* __restrict__ b1a, const float* __restrict__ b2a,
    const u16* __restrict__ W1T, const u16* __restrict__ W2T,
    float* __restrict__ x)
{
    __shared__ __align__(16) unsigned char smem[38912];
    u16*   hz    = (u16*)smem;                        // 32 KB
    float* bondL = (float*)(smem + 32768);            // 5 KB
    u16*   permL = (u16*)(smem + 32768 + 5120);
    u16*   offL  = (u16*)(smem + 32768 + 5120 + 256);
    float* validL= (float*)(smem + 32768 + 5120 + 512);
    float* epsL  = (float*)(smem + 32768 + 5120 + 512 + 256);

    int tid = threadIdx.x, lane = tid & 63, wave = tid >> 6;
    int row0 = blockIdx.x * 64;
    int fr = lane & 15, quad = lane >> 4;

    for (int i = tid; i < EDN * 256; i += 256) bondL[i] = bond_emb[i];
    if (tid < 128) permL[tid] = perm[blockIdx.x * 128 + tid];
    if (tid < 64) {
        offL[tid] = off[blockIdx.x * 64 + tid];
        validL[tid] = (nodes[row0 + tid] >= 0) ? 1.0f : 0.0f;
    }
    if (tid < 4) epsL[tid] = eps_arr[tid];

    {   // h init directly into hz
        int m = tid & 63, qd = tid >> 6;
        int rg = row0 + m;
        float valid = (nodes[rg] >= 0) ? 1.0f : 0.0f;
        float lpv = finite_or_zero(lp[rg >> 5]);
        int dc = dist[rg]; dc = dc < 0 ? 0 : (dc > MAXD ? MAXD : dc);
        int xid = x_ids[rg];
        #pragma unroll
        for (int k = 0; k < 8; ++k) {
            int cc = qd * 8 + k, c = cc * 8;
            float4 a0 = *reinterpret_cast<const float4*>(atom_emb + xid * 256 + c);
            float4 a1 = *reinterpret_cast<const float4*>(atom_emb + xid * 256 + c + 4);
            float4 d0 = *reinterpret_cast<const float4*>(dist_emb + dc * 256 + c);
            float4 d1 = *reinterpret_cast<const float4*>(dist_emb + dc * 256 + c + 4);
            float4 w0 = *reinterpret_cast<const float4*>(logp_W + c);
            float4 w1 = *reinterpret_cast<const float4*>(logp_W + c + 4);
            float4 p0 = *reinterpret_cast<const float4*>(logp_b + c);
            float4 p1 = *reinterpret_cast<const float4*>(logp_b + c + 4);
            union { bf16x8 v; ushort4 h[2]; } o;
            o.h[0] = (ushort4){
                f2us((a0.x + d0.x + fmaxf(lpv * w0.x + p0.x, 0.f)) * valid),
                f2us((a0.y + d0.y + fmaxf(lpv * w0.y + p0.y, 0.f)) * valid),
                f2us((a0.z + d0.z + fmaxf(lpv * w0.z + p0.z, 0.f)) * valid),
                f2us((a0.w + d0.w + fmaxf(lpv * w0.w + p0.w, 0.f)) * valid) };
            o.h[1] = (ushort4){
                f2us((a1.x + d1.x + fmaxf(lpv * w1.x + p1.x, 0.f)) * valid),
                f2us((a1.y + d1.y + fmaxf(lpv * w1.y + p1.y, 0.f)) * valid),
                f2us((a1.z + d1.z + fmaxf(lpv * w1.z + p1.z, 0.f)) * valid),
                f2us((a1.w + d1.w + fmaxf(lpv * w1.w + p1.w, 0.f)) * valid) };
            *reinterpret_cast<bf16x8*>(hz + m * 256 + ((cc ^ (m & 7)) * 8)) = o.v;
        }
    }
    __syncthreads();

    int rl = tid >> 3, g8 = tid & 7;
    for (int l = 0; l < LLAY; ++l) {
        float ep1 = 1.0f + epsL[l];
        for (int p = 0; p < 2; ++p) {
            int row = p * 32 + rl;
            int e0 = offL[p * 32 + rl];
            int e1 = (rl < 31) ? offL[p * 32 + rl + 1] : 64;
            float a[32];
            #pragma unroll
            for (int q = 0; q < 32; ++q) a[q] = 0.f;
            for (int j = e0; j < e1; ++j) {
                int ent = permL[p * 64 + j];
                int sl = p * 32 + (ent >> 3);
                int be = ent & 7;
                #pragma unroll
                for (int q = 0; q < 4; ++q) {
                    union { bf16x8 v; u16 s[8]; } hv;
                    hv.v = *reinterpret_cast<const bf16x8*>(
                        hz + sl * 256 + (((g8 * 4 + q) ^ (sl & 7)) * 8));
                    const float* bp = bondL + be * 256 + g8 * 32 + q * 8;
                    float4 bo0 = *reinterpret_cast<const float4*>(bp);
                    float4 bo1 = *reinterpret_cast<const float4*>(bp + 4);
                    a[q*8+0] += fmaxf(us2f(hv.s[0]) + bo0.x, 0.f);
                    a[q*8+1] += fmaxf(us2f(hv.s[1]) + bo0.y, 0.f);
                    a[q*8+2] += fmaxf(us2f(hv.s[2]) + bo0.z, 0.f);
                    a[q*8+3] += fmaxf(us2f(hv.s[3]) + bo0.w, 0.f);
                    a[q*8+4] += fmaxf(us2f(hv.s[4]) + bo1.x, 0.f);
                    a[q*8+5] += fmaxf(us2f(hv.s[5]) + bo1.y, 0.f);
                    a[q*8+6] += fmaxf(us2f(hv.s[6]) + bo1.z, 0.f);
                    a[q*8+7] += fmaxf(us2f(hv.s[7]) + bo1.w, 0.f);
                }
            }
            __syncthreads();
            #pragma unroll
            for (int q = 0; q < 4; ++q) {
                u16* ptr = hz + row * 256 + (((g8 * 4 + q) ^ (row & 7)) * 8);
                union { bf16x8 v; u16 s[8]; } hv, ov;
                hv.v = *reinterpret_cast<const bf16x8*>(ptr);
                #pragma unroll
                for (int k = 0; k < 8; ++k)
                    ov.s[k] = f2us(ep1 * us2f(hv.s[k]) + a[q * 8 + k]);
                *reinterpret_cast<bf16x8*>(ptr) = ov.v;
            }
        }
        __syncthreads();

        const u16* W1 = W1T + l * 65536;
        const float* b1 = b1a + l * 256;
        bf16x8 wf[4][8];
        #pragma unroll
        for (int i = 0; i < 4; ++i)
            #pragma unroll
            for (int kc = 0; kc < 8; ++kc)
                wf[i][kc] = *reinterpret_cast<const bf16x8*>(
                    W1 + (size_t)(wave * 64 + i * 16 + fr) * 256 + kc * 32 + quad * 8);
        f32x4 acc[4][4];
        #pragma unroll
        for (int i = 0; i < 4; ++i)
            #pragma unroll
            for (int j = 0; j < 4; ++j) acc[i][j] = (f32x4){0.f, 0.f, 0.f, 0.f};
        #pragma unroll
        for (int kc = 0; kc < 8; ++kc) {
            bf16x8 bfv[4];
            #pragma unroll
            for (int j = 0; j < 4; ++j) {
                int m = j * 16 + fr;
                bfv[j] = *reinterpret_cast<const bf16x8*>(hz + m * 256 + (((kc * 4 + quad) ^ (m & 7)) * 8));
            }
            #pragma unroll
            for (int i = 0; i < 4; ++i)
                #pragma unroll
                for (int j = 0; j < 4; ++j)
                    acc[i][j] = __builtin_amdgcn_mfma_f32_16x16x32_bf16(wf[i][kc], bfv[j], acc[i][j], 0, 0, 0);
        }
        __syncthreads();
        #pragma unroll
        for (int i = 0; i < 4; ++i) {
            int n1b = wave * 64 + i * 16 + quad * 4;
            float4 bb = *reinterpret_cast<const float4*>(b1 + n1b);
            #pragma unroll
            for (int j = 0; j < 4; ++j) {
                int m = j * 16 + fr;
                ushort4 o = { f2us(fmaxf(acc[i][j][0] + bb.x, 0.f)),
                              f2us(fmaxf(acc[i][j][1] + bb.y, 0.f)),
                              f2us(fmaxf(acc[i][j][2] + bb.z, 0.f)),
                              f2us(fmaxf(acc[i][j][3] + bb.w, 0.f)) };
                *reinterpret_cast<ushort4*>(hz + m * 256 + (((n1b >> 3) ^ (m & 7)) * 8) + (n1b & 7)) = o;
            }
        }
        __syncthreads();

        const u16* W2 = W2T + l * 65536;
        const float* b2 = b2a + l * 256;
        #pragma unroll
        for (int i = 0; i < 4; ++i)
            #pragma unroll
            for (int kc = 0; kc < 8; ++kc)
                wf[i][kc] = *reinterpret_cast<const bf16x8*>(
                    W2 + (size_t)(wave * 64 + i * 16 + fr) * 256 + kc * 32 + quad * 8);
        #pragma unroll
        for (int i = 0; i < 4; ++i)
            #pragma unroll
            for (int j = 0; j < 4; ++j) acc[i][j] = (f32x4){0.f, 0.f, 0.f, 0.f};
        #pragma unroll
        for (int kc = 0; kc < 8; ++kc) {
            bf16x8 bfv[4];
            #pragma unroll
            for (int j = 0; j < 4; ++j) {
                int m = j * 16 + fr;
                bfv[j] = *reinterpret_cast<const bf16x8*>(hz + m * 256 + (((kc * 4 + quad) ^ (m & 7)) * 8));
            }
            #pragma unroll
            for (int i = 0; i < 4; ++i)
                #pragma unroll
                for (int j = 0; j < 4; ++j)
                    acc[i][j] = __builtin_amdgcn_mfma_f32_16x16x32_bf16(wf[i][kc], bfv[j], acc[i][j], 0, 0, 0);
        }
        __syncthreads();

        if (l < LLAY - 1) {
            #pragma unroll
            for (int i = 0; i < 4; ++i) {
                int n2b = wave * 64 + i * 16 + quad * 4;
                float4 bb = *reinterpret_cast<const float4*>(b2 + n2b);
                #pragma unroll
                for (int j = 0; j < 4; ++j) {
                    int m = j * 16 + fr;
                    float vm = validL[m];
                    ushort4 o = { f2us((acc[i][j][0] + bb.x) * vm),
                                  f2us((acc[i][j][1] + bb.y) * vm),
                                  f2us((acc[i][j][2] + bb.z) * vm),
                                  f2us((acc[i][j][3] + bb.w) * vm) };
                    *reinterpret_cast<ushort4*>(hz + m * 256 + (((n2b >> 3) ^ (m & 7)) * 8) + (n2b & 7)) = o;
                }
            }
            __syncthreads();
        } else {
            if (fr == 0) {
                #pragma unroll
                for (int i = 0; i < 4; ++i) {
                    int n2b = wave * 64 + i * 16 + quad * 4;
                    float4 bb = *reinterpret_cast<const float4*>(b2 + n2b);
                    #pragma unroll
                    for (int jj = 0; jj < 2; ++jj) {
                        int j = jj * 2, m = j * 16;          // m = 0, 32
                        float vm = validL[m];
                        float4 o = { (acc[i][j][0] + bb.x) * vm,
                                     (acc[i][j][1] + bb.y) * vm,
                                     (acc[i][j][2] + bb.z) * vm,
                                     (acc[i][j][3] + bb.w) * vm };
                        *reinterpret_cast<float4*>(
                            x + (size_t)(blockIdx.x * 2 + (m >> 5)) * 256 + n2b) = o;
                    }
                }
            }
        }
    }
}

// ---------------------------------------------------------------------------
// Fully-fused transformer: bias + 4 layers (LN1,qkv,attn,out,LN2,f1,f2)
// + final LN + softmax-weighted sum. One block = one batch (32 rows).
// x stays LDS-resident (f32, row stride 260 to spread banks). Weights are
// pre-transposed bf16 (N x K), streamed L2->registers per kc step.
// LDS layout (bytes):
#define TF_XF    0          // f32[32][260]  = 33280
#define TF_RB    33280      // u16[32][256] swizzled = 16384
#define TF_BIAS  49664      // f32[32][33]   = 4224
#define TF_LPC   53888      // f32[32]
#define TF_WFIN  54016      // f32[32]
#define TF_EMB   54144      // f32[16]
#define TF_U     54272      // union region
#define TF_QKV   54272      // u16[32][768] swizzled = 49152
#define TF_QS    103424     // f32[32][65] = 8320
#define TF_KS    111744
#define TF_VS    120064
#define TF_SC    128384     // f32[32][33] = 4224
#define TF_OB    132608     // u16[32][256] swizzled = 16384 -> ends 148992
#define TF_FFH   54272      // u16[32][1024] swizzled = 65536 (aliases QKV..KS)
#define TF_XLN   54272      // f32[32][260] (after layers)
#define XSTR 260
__global__ __launch_bounds__(256, 1) void k_tformer(
    const float* __restrict__ x, const int* __restrict__ nodes,
    const float* __restrict__ lp, const float* __restrict__ ovl_emb,
    const float* __restrict__ alpha_p,
    const float* __restrict__ ln1_g, const float* __restrict__ ln1_b,
    const u16* __restrict__ qkvT, const u16* __restrict__ outT,
    const float* __restrict__ out_b,
    const float* __restrict__ ln2_g, const float* __restrict__ ln2_b,
    const u16* __restrict__ f1T, const float* __restrict__ f1_b,
    const u16* __restrict__ f2T, const float* __restrict__ f2_b,
    const float* __restrict__ lnout_g, const float* __restrict__ lnout_b,
    float* __restrict__ out)
{
    __shared__ __align__(16) unsigned char smem[148992];
    float* xf   = (float*)(smem + TF_XF);
    u16*   rb   = (u16*)(smem + TF_RB);
    float* biasL= (float*)(smem + TF_BIAS);
    float* lpc  = (float*)(smem + TF_LPC);
    float* wfin = (float*)(smem + TF_WFIN);
    float* emb  = (float*)(smem + TF_EMB);
    u16*   qkvb = (u16*)(smem + TF_QKV);
    float* qs   = (float*)(smem + TF_QS);
    float* ks   = (float*)(smem + TF_KS);
    float* vs   = (float*)(smem + TF_VS);
    float* sc   = (float*)(smem + TF_SC);
    u16*   obL  = (u16*)(smem + TF_OB);
    u16*   ffh  = (u16*)(smem + TF_FFH);
    float* xlnf = (float*)(smem + TF_XLN);

    int tid = threadIdx.x, lane = tid & 63, wave = tid >> 6;
    int b = blockIdx.x;
    int fr = lane & 15, quad = lane >> 4;

    // ---- load x rows into xf ----
    #pragma unroll
    for (int u = 0; u < 8; ++u) {
        int v = u * 256 + tid;            // 2048 float4 units
        int i = v >> 6, c = (v & 63) * 4;
        *reinterpret_cast<float4*>(xf + i * XSTR + c) =
            *reinterpret_cast<const float4*>(x + (size_t)(b * 32 + i) * 256 + c);
    }
    // ---- bias prologue (bitmap overlap), scratch in U region ----
    {
        int* nd = (int*)(smem + TF_U);                       // 4 KB
        unsigned int* bmv = (unsigned int*)(smem + TF_U + 4096); // 32x17
        #pragma unroll
        for (int u = 0; u < 4; ++u) nd[tid + u * 256] = nodes[b * 1024 + tid + u * 256];
        for (int i = tid; i < 544; i += 256) bmv[i] = 0u;
        if (tid < 32) {
            float l = finite_or_zero(lp[b * 32 + tid]);
            l = l < -30.f ? -30.f : (l > 0.f ? 0.f : l);
            lpc[tid] = l;
        }
        if (tid <= KMAXC) emb[tid] = ovl_emb[tid];
        __syncthreads();
        #pragma unroll
        for (int u = 0; u < 4; ++u) {
            int p = tid + u * 256;
            int own = nd[p];
            if (own >= 0) atomicOr(&bmv[(p >> 5) * 17 + (own >> 5)], 1u << (own & 31));
        }
        __syncthreads();
        float alpha = alpha_p[0];
        #pragma unroll
        for (int u = 0; u < 4; ++u) {
            int p = tid + u * 256;
            int i = p >> 5, j = p & 31;
            int cnt = 0;
            #pragma unroll
            for (int k = 0; k < 32; ++k) {
                int nk = nd[i * 32 + k];
                if (nk >= 0) cnt += (int)((bmv[j * 17 + (nk >> 5)] >> (nk & 31)) & 1u);
            }
            biasL[i * 33 + j] = emb[cnt > KMAXC ? KMAXC : cnt] - alpha * lpc[j];
        }
    }
    __syncthreads();

    for (int t = 0; t < TLAY; ++t) {
        // ---- LN1: xf -> rb (bf16 swizzled) ----
        {
            const float* g = ln1_g + t * 256;
            const float* bb = ln1_b + t * 256;
            #pragma unroll
            for (int rr = 0; rr < 8; ++rr) {
                int row = wave * 8 + rr;
                float4 xv = *reinterpret_cast<const float4*>(xf + row * XSTR + lane * 4);
                float s = xv.x + xv.y + xv.z + xv.w;
                #pragma unroll
                for (int o2 = 32; o2 > 0; o2 >>= 1) s += __shfl_xor(s, o2);
                float mu = s * (1.0f / 256.0f);
                float d0 = xv.x - mu, d1 = xv.y - mu, d2 = xv.z - mu, d3 = xv.w - mu;
                float sq = d0 * d0 + d1 * d1 + d2 * d2 + d3 * d3;
                #pragma unroll
                for (int o2 = 32; o2 > 0; o2 >>= 1) sq += __shfl_xor(sq, o2);
                float rs = rsqrtf(sq * (1.0f / 256.0f) + 1e-5f);
                int c = lane * 4;
                float4 gv = *reinterpret_cast<const float4*>(g + c);
                float4 bv = *reinterpret_cast<const float4*>(bb + c);
                ushort4 o = { f2us(d0 * rs * gv.x + bv.x), f2us(d1 * rs * gv.y + bv.y),
                              f2us(d2 * rs * gv.z + bv.z), f2us(d3 * rs * gv.w + bv.w) };
                *reinterpret_cast<ushort4*>(rb + row * 256 + (((c >> 3) ^ (row & 7)) * 8) + (c & 7)) = o;
            }
        }
        __syncthreads();
        // ---- qkv: qkvb[m][n] = rb @ qkvT^T (no bias); 12 n-tiles/wave ----
        {
            const u16* W = qkvT + (size_t)t * 768 * 256;
            f32x4 acc[12][2];
            #pragma unroll
            for (int i = 0; i < 12; ++i) { acc[i][0] = (f32x4){0,0,0,0}; acc[i][1] = (f32x4){0,0,0,0}; }
            for (int kc = 0; kc < 8; ++kc) {
                bf16x8 wf[12], bfv[2];
                #pragma unroll
                for (int i = 0; i < 12; ++i)
                    wf[i] = *reinterpret_cast<const bf16x8*>(
                        W + (size_t)((wave * 12 + i) * 16 + fr) * 256 + kc * 32 + quad * 8);
                #pragma unroll
                for (int j = 0; j < 2; ++j) {
                    int m = j * 16 + fr;
                    bfv[j] = *reinterpret_cast<const bf16x8*>(rb + m * 256 + (((kc * 4 + quad) ^ (m & 7)) * 8));
                }
                #pragma unroll
                for (int i = 0; i < 12; ++i)
                    #pragma unroll
                    for (int j = 0; j < 2; ++j)
                        acc[i][j] = __builtin_amdgcn_mfma_f32_16x16x32_bf16(wf[i], bfv[j], acc[i][j], 0, 0, 0);
            }
            __syncthreads();
            #pragma unroll
            for (int i = 0; i < 12; ++i) {
                int n1b = (wave * 12 + i) * 16 + quad * 4;
                #pragma unroll
                for (int j = 0; j < 2; ++j) {
                    int m = j * 16 + fr;
                    ushort4 o = { f2us(acc[i][j][0]), f2us(acc[i][j][1]),
                                  f2us(acc[i][j][2]), f2us(acc[i][j][3]) };
                    *reinterpret_cast<ushort4*>(qkvb + m * 768 + (((n1b >> 3) ^ (m & 7)) * 8) + (n1b & 7)) = o;
                }
            }
        }
        __syncthreads();
        // ---- attention: per head, verified k_attn body, qkv from LDS ----
        for (int hh = 0; hh < NHEAD; ++hh) {
            #pragma unroll
            for (int u = 0; u < 8; ++u) {
                int idx = tid + u * 256;
                int i = idx >> 6, d = idx & 63;
                int cq = hh * 64 + d, ck = 256 + hh * 64 + d, cv = 512 + hh * 64 + d;
                qs[i * 65 + d] = us2f(qkvb[i * 768 + (((cq >> 3) ^ (i & 7)) * 8) + (cq & 7)]);
                ks[i * 65 + d] = us2f(qkvb[i * 768 + (((ck >> 3) ^ (i & 7)) * 8) + (ck & 7)]);
                vs[i * 65 + d] = us2f(qkvb[i * 768 + (((cv >> 3) ^ (i & 7)) * 8) + (cv & 7)]);
            }
            __syncthreads();
            #pragma unroll
            for (int u = 0; u < 4; ++u) {
                int p = tid + u * 256;
                int i = p >> 5, j = p & 31;
                float s = 0.f;
                #pragma unroll
                for (int d = 0; d < 64; ++d) s += qs[i * 65 + d] * ks[j * 65 + d];
                sc[i * 33 + j] = s * 0.125f + biasL[i * 33 + j];
            }
            __syncthreads();
            if (tid < 32) {
                int i = tid;
                float m = -1e30f;
                for (int j = 0; j < 32; ++j) m = fmaxf(m, sc[i * 33 + j]);
                float sum = 0.f;
                for (int j = 0; j < 32; ++j) { float e = expf(sc[i * 33 + j] - m); sc[i * 33 + j] = e; sum += e; }
                float inv = 1.0f / sum;
                for (int j = 0; j < 32; ++j) sc[i * 33 + j] *= inv;
            }
            __syncthreads();
            #pragma unroll
            for (int u = 0; u < 8; ++u) {
                int idx = tid + u * 256;
                int i = idx >> 6, d = idx & 63;
                float a = 0.f;
                #pragma unroll
                for (int j = 0; j < 32; ++j) a += sc[i * 33 + j] * vs[j * 65 + d];
                int c = hh * 64 + d;
                obL[i * 256 + (((c >> 3) ^ (i & 7)) * 8) + (c & 7)] = f2us(a);
            }
            __syncthreads();
        }
        // ---- out-proj + residual: xf += obL @ outT^T + out_b ----
        {
            const u16* W = outT + (size_t)t * 65536;
            const float* bb = out_b + t * 256;
            f32x4 acc[4][2];
            #pragma unroll
            for (int i = 0; i < 4; ++i) { acc[i][0] = (f32x4){0,0,0,0}; acc[i][1] = (f32x4){0,0,0,0}; }
            for (int kc = 0; kc < 8; ++kc) {
                bf16x8 wf[4], bfv[2];
                #pragma unroll
                for (int i = 0; i < 4; ++i)
                    wf[i] = *reinterpret_cast<const bf16x8*>(
                        W + (size_t)((wave * 4 + i) * 16 + fr) * 256 + kc * 32 + quad * 8);
                #pragma unroll
                for (int j = 0; j < 2; ++j) {
                    int m = j * 16 + fr;
                    bfv[j] = *reinterpret_cast<const bf16x8*>(obL + m * 256 + (((kc * 4 + quad) ^ (m & 7)) * 8));
                }
                #pragma unroll
                for (int i = 0; i < 4; ++i)
                    #pragma unroll
                    for (int j = 0; j < 2; ++j)
                        acc[i][j] = __builtin_amdgcn_mfma_f32_16x16x32_bf16(wf[i], bfv[j], acc[i][j], 0, 0, 0);
            }
            __syncthreads();
            #pragma unroll
            for (int i = 0; i < 4; ++i) {
                int n1b = (wave * 4 + i) * 16 + quad * 4;
                float4 bv = *reinterpret_cast<const float4*>(bb + n1b);
                #pragma unroll
                for (int j = 0; j < 2; ++j) {
                    int m = j * 16 + fr;
                    float4* px = reinterpret_cast<float4*>(xf + m * XSTR + n1b);
                    float4 xv = *px;
                    xv.x += acc[i][j][0] + bv.x; xv.y += acc[i][j][1] + bv.y;
                    xv.z += acc[i][j][2] + bv.z; xv.w += acc[i][j][3] + bv.w;
                    *px = xv;
                }
            }
        }
        __syncthreads();
        // ---- LN2: xf -> rb ----
        {
            const float* g = ln2_g + t * 256;
            const float* bb = ln2_b + t * 256;
            #pragma unroll
            for (int rr = 0; rr < 8; ++rr) {
                int row = wave * 8 + rr;
                float4 xv = *reinterpret_cast<const float4*>(xf + row * XSTR + lane * 4);
                float s = xv.x + xv.y + xv.z + xv.w;
                #pragma unroll
                for (int o2 = 32; o2 > 0; o2 >>= 1) s += __shfl_xor(s, o2);
                float mu = s * (1.0f / 256.0f);
                float d0 = xv.x - mu, d1 = xv.y - mu, d2 = xv.z - mu, d3 = xv.w - mu;
                float sq = d0 * d0 + d1 * d1 + d2 * d2 + d3 * d3;
                #pragma unroll
                for (int o2 = 32; o2 > 0; o2 >>= 1) sq += __shfl_xor(sq, o2);
                float rs = rsqrtf(sq * (1.0f / 256.0f) + 1e-5f);
                int c = lane * 4;
                float4 gv = *reinterpret_cast<const float4*>(g + c);
                float4 bv = *reinterpret_cast<const float4*>(bb + c);
                ushort4 o = { f2us(d0 * rs * gv.x + bv.x), f2us(d1 * rs * gv.y + bv.y),
                              f2us(d2 * rs * gv.z + bv.z), f2us(d3 * rs * gv.w + bv.w) };
                *reinterpret_cast<ushort4*>(rb + row * 256 + (((c >> 3) ^ (row & 7)) * 8) + (c & 7)) = o;
            }
        }
        __syncthreads();
        // ---- f1: ffh = gelu(rb @ f1T^T + f1_b); 16 n-tiles/wave ----
        {
            const u16* W = f1T + (size_t)t * 1024 * 256;
            const float* bb = f1_b + t * 1024;
            f32x4 acc[16][2];
            #pragma unroll
            for (int i = 0; i < 16; ++i) { acc[i][0] = (f32x4){0,0,0,0}; acc[i][1] = (f32x4){0,0,0,0}; }
            for (int kc = 0; kc < 8; ++kc) {
                bf16x8 wf[16], bfv[2];
                #pragma unroll
                for (int i = 0; i < 16; ++i)
                    wf[i] = *reinterpret_cast<const bf16x8*>(
                        W + (size_t)((wave * 16 + i) * 16 + fr) * 256 + kc * 32 + quad * 8);
                #pragma unroll
                for (int j = 0; j < 2; ++j) {
                    int m = j * 16 + fr;
                    bfv[j] = *reinterpret_cast<const bf16x8*>(rb + m * 256 + (((kc * 4 + quad) ^ (m & 7)) * 8));
                }
                #pragma unroll
                for (int i = 0; i < 16; ++i)
                    #pragma unroll
                    for (int j = 0; j < 2; ++j)
                        acc[i][j] = __builtin_amdgcn_mfma_f32_16x16x32_bf16(wf[i], bfv[j], acc[i][j], 0, 0, 0);
            }
            __syncthreads();
            #pragma unroll
            for (int i = 0; i < 16; ++i) {
                int n1b = (wave * 16 + i) * 16 + quad * 4;
                float4 bv = *reinterpret_cast<const float4*>(bb + n1b);
                #pragma unroll
                for (int j = 0; j < 2; ++j) {
                    int m = j * 16 + fr;
                    float v0 = acc[i][j][0] + bv.x, v1 = acc[i][j][1] + bv.y;
                    float v2 = acc[i][j][2] + bv.z, v3 = acc[i][j][3] + bv.w;
                    v0 = 0.5f * v0 * (1.0f + erff(v0 * 0.70710678118654752f));
                    v1 = 0.5f * v1 * (1.0f + erff(v1 * 0.70710678118654752f));
                    v2 = 0.5f * v2 * (1.0f + erff(v2 * 0.70710678118654752f));
                    v3 = 0.5f * v3 * (1.0f + erff(v3 * 0.70710678118654752f));
                    ushort4 o = { f2us(v0), f2us(v1), f2us(v2), f2us(v3) };
                    *reinterpret_cast<ushort4*>(ffh + m * 1024 + (((n1b >> 3) ^ (m & 7)) * 8) + (n1b & 7)) = o;
                }
            }
        }
        __syncthreads();
        // ---- f2: xf += ffh @ f2T^T + f2_b (K=1024) ----
        {
            const u16* W = f2T + (size_t)t * 256 * 1024;
            const float* bb = f2_b + t * 256;
            f32x4 acc[4][2];
            #pragma unroll
            for (int i = 0; i < 4; ++i) { acc[i][0] = (f32x4){0,0,0,0}; acc[i][1] = (f32x4){0,0,0,0}; }
            for (int kc = 0; kc < 32; ++kc) {
                bf16x8 wf[4], bfv[2];
                #pragma unroll
                for (int i = 0; i < 4; ++i)
                    wf[i] = *reinterpret_cast<const bf16x8*>(
                        W + (size_t)((wave * 4 + i) * 16 + fr) * 1024 + kc * 32 + quad * 8);
                #pragma unroll
                for (int j = 0; j < 2; ++j) {
                    int m = j * 16 + fr;
                    bfv[j] = *reinterpret_cast<const bf16x8*>(ffh + m * 1024 + (((kc * 4 + quad) ^ (m & 7)) * 8));
                }
                #pragma unroll
                for (int i = 0; i < 4; ++i)
                    #pragma unroll
                    for (int j = 0; j < 2; ++j)
                        acc[i][j] = __builtin_amdgcn_mfma_f32_16x16x32_bf16(wf[i], bfv[j], acc[i][j], 0, 0, 0);
            }
            __syncthreads();
            #pragma unroll
            for (int i = 0; i < 4; ++i) {
                int n1b = (wave * 4 + i) * 16 + quad * 4;
                float4 bv = *reinterpret_cast<const float4*>(bb + n1b);
                #pragma unroll
                for (int j = 0; j < 2; ++j) {
                    int m = j * 16 + fr;
                    float4* px = reinterpret_cast<float4*>(xf + m * XSTR + n1b);
                    float4 xv = *px;
                    xv.x += acc[i][j][0] + bv.x; xv.y += acc[i][j][1] + bv.y;
                    xv.z += acc[i][j][2] + bv.z; xv.w += acc[i][j][3] + bv.w;
                    *px = xv;
                }
            }
        }
        __syncthreads();
    }

    // ---- final LN -> xlnf (f32), weights, weighted sum -> out ----
    #pragma unroll
    for (int rr = 0; rr < 8; ++rr) {
        int row = wave * 8 + rr;
        float4 xv = *reinterpret_cast<const float4*>(xf + row * XSTR + lane * 4);
        float s = xv.x + xv.y + xv.z + xv.w;
        #pragma unroll
        for (int o2 = 32; o2 > 0; o2 >>= 1) s += __shfl_xor(s, o2);
        float mu = s * (1.0f / 256.0f);
        float d0 = xv.x - mu, d1 = xv.y - mu, d2 = xv.z - mu, d3 = xv.w - mu;
        float sq = d0 * d0 + d1 * d1 + d2 * d2 + d3 * d3;
        #pragma unroll
        for (int o2 = 32; o2 > 0; o2 >>= 1) sq += __shfl_xor(sq, o2);
        float rs = rsqrtf(sq * (1.0f / 256.0f) + 1e-5f);
        int c = lane * 4;
        float4 gv = *reinterpret_cast<const float4*>(lnout_g + c);
        float4 bv = *reinterpret_cast<const float4*>(lnout_b + c);
        float4 o = { d0 * rs * gv.x + bv.x, d1 * rs * gv.y + bv.y,
                     d2 * rs * gv.z + bv.z, d3 * rs * gv.w + bv.w };
        *reinterpret_cast<float4*>(xlnf + row * XSTR + c) = o;
    }
    if (tid == 0) {
        float m = -1e30f;
        for (int i = 0; i < 32; ++i) m = fmaxf(m, -lpc[i]);
        float s = 0.f;
        for (int i = 0; i < 32; ++i) { float e = expf(-lpc[i] - m); wfin[i] = e; s += e; }
        float inv = 1.0f / s;
        for (int i = 0; i < 32; ++i) wfin[i] *= inv;
    }
    __syncthreads();
    {
        float a = 0.f;
        for (int i = 0; i < 32; ++i) a += wfin[i] * xlnf[i * XSTR + tid];
        out[(size_t)b * 256 + tid] = a;
    }
}

// ---------------------------------------------------------------------------
extern "C" void kernel_launch(void* const* d_in, const int* in_sizes, int n_in,
                              void* d_out, int out_size, void* d_ws, size_t ws_size,
                              hipStream_t stream)
{
    const int*   x_ids    = (const int*)d_in[0];
    const int*   edge_ids = (const int*)d_in[1];
    const int*   srcp     = (const int*)d_in[2];
    const int*   dstp     = (const int*)d_in[3];
    const int*   nodes    = (const int*)d_in[4];
    const int*   dist     = (const int*)d_in[5];
    const float* lp       = (const float*)d_in[6];
    const float* atom_emb = (const float*)d_in[7];
    const float* bond_emb = (const float*)d_in[8];
    const float* dist_emb = (const float*)d_in[9];
    const float* logp_W   = (const float*)d_in[10];
    const float* logp_b   = (const float*)d_in[11];
    const float* gnn_eps  = (const float*)d_in[12];
    const float* gnn_W1   = (const float*)d_in[13];
    const float* gnn_b1   = (const float*)d_in[14];
    const float* gnn_W2   = (const float*)d_in[15];
    const float* gnn_b2   = (const float*)d_in[16];
    const float* ln1_g    = (const float*)d_in[17];
    const float* ln1_b    = (const float*)d_in[18];
    const float* qkv_W    = (const float*)d_in[19];
    const float* out_W    = (const float*)d_in[20];
    const float* out_b    = (const float*)d_in[21];
    const float* ln2_g    = (const float*)d_in[22];
    const float* ln2_b    = (const float*)d_in[23];
    const float* f1_W     = (const float*)d_in[24];
    const float* f1_b     = (const float*)d_in[25];
    const float* f2_W     = (const float*)d_in[26];
    const float* f2_b     = (const float*)d_in[27];
    const float* lnout_g  = (const float*)d_in[28];
    const float* lnout_b  = (const float*)d_in[29];
    const float* ovl_emb  = (const float*)d_in[30];
    const float* alpha    = (const float*)d_in[31];

    char* ws = (char*)d_ws;
    u16*   gW1T  = (u16*)(ws + 100663296ull);                // 512 KB
    u16*   gW2T  = (u16*)(ws + 100663296ull + 524288ull);    // 512 KB
    u16*   permW = (u16*)(ws + 100663296ull + 1048576ull);   // 256 KB
    u16*   offW  = (u16*)(ws + 100663296ull + 1310720ull);   // 128 KB
    u16*   qkvT  = (u16*)(ws + 33554432ull);                 // 1.5 MB
    u16*   outT  = (u16*)(ws + 33554432ull + 1572864ull);    // 512 KB
    u16*   f1T   = (u16*)(ws + 33554432ull + 2097152ull);    // 2 MB
    u16*   f2T   = (u16*)(ws + 33554432ull + 4194304ull);    // 2 MB
    float* x     = (float*)(ws + 67108864ull);               // 2 MB f32

    k_csr<<<SSUB / 4, 256, 0, stream>>>(srcp, dstp, edge_ids, permW, offW);
    k_wtrans<<<dim3(8, 8, 4), 256, 0, stream>>>(gnn_W1, gW1T, 256, 256);
    k_wtrans<<<dim3(8, 8, 4), 256, 0, stream>>>(gnn_W2, gW2T, 256, 256);
    k_gnn4<<<NNODE / 64, 256, 0, stream>>>(
        x_ids, dist, nodes, lp, atom_emb, dist_emb, logp_W, logp_b,
        permW, offW, bond_emb, gnn_eps, gnn_b1, gnn_b2, gW1T, gW2T, x);
    k_wtrans<<<dim3(8, 24, 4), 256, 0, stream>>>(qkv_W, qkvT, 256, 768);
    k_wtrans<<<dim3(8, 8, 4), 256, 0, stream>>>(out_W, outT, 256, 256);
    k_wtrans<<<dim3(8, 32, 4), 256, 0, stream>>>(f1_W, f1T, 256, 1024);
    k_wtrans<<<dim3(32, 8, 4), 256, 0, stream>>>(f2_W, f2T, 1024, 256);
    k_tformer<<<BATCH, 256, 0, stream>>>(
        x, nodes, lp, ovl_emb, alpha,
        ln1_g, ln1_b, qkvT, outT, out_b, ln2_g, ln2_b,
        f1T, f1_b, f2T, f2_b, lnout_g, lnout_b, (float*)d_out);
}

// Round 11
// 598.326 us; speedup vs baseline: 1.4800x; 1.4800x over previous
//
#include <hip/hip_runtime.h>
#include <hip/hip_bf16.h>
#include <math.h>

#define HDIM   256
#define NHEAD  4
#define LLAY   4
#define TLAY   4
#define KMAXC  10
#define MAXD   32
#define BATCH  64
#define MSUB   32
#define KNODE  32
#define SSUB   2048
#define NNODE  65536
#define NEDGE  131072
#define EPSPER 64
#define EDN    5

typedef unsigned short u16;
typedef __attribute__((ext_vector_type(8))) short bf16x8;
typedef __attribute__((ext_vector_type(4))) float f32x4;

__device__ __forceinline__ float us2f(u16 u) {
    union { unsigned int i; float f; } x; x.i = ((unsigned int)u) << 16; return x.f;
}
__device__ __forceinline__ u16 f2us(float v) {
    union { float f; unsigned int i; } x; x.f = v;
    unsigned int u = x.i;
    u += 0x7fffu + ((u >> 16) & 1u);   // RNE
    return (u16)(u >> 16);
}
__device__ __forceinline__ float finite_or_zero(float v) {
    return (v == v && fabsf(v) <= 3.0e38f) ? v : 0.0f;
}
__device__ __forceinline__ void gll16(const u16* g, u16* l) {
    __builtin_amdgcn_global_load_lds(
        (const __attribute__((address_space(1))) unsigned int*)g,
        (__attribute__((address_space(3))) unsigned int*)l, 16, 0, 0);
}

// ---------------------------------------------------------------------------
// CSR precompute: per subgraph, edges sorted by local dst row.
__global__ __launch_bounds__(256) void k_csr(
    const int* __restrict__ src, const int* __restrict__ dst,
    const int* __restrict__ eid, u16* __restrict__ perm, u16* __restrict__ off)
{
    __shared__ int sL[4][64], dL[4][64], eL[4][64];
    int wave = threadIdx.x >> 6, lane = threadIdx.x & 63;
    int sgi = blockIdx.x * 4 + wave;
    sL[wave][lane] = src[sgi * 64 + lane] - sgi * KNODE;
    dL[wave][lane] = dst[sgi * 64 + lane] - sgi * KNODE;
    eL[wave][lane] = eid[sgi * 64 + lane];
    __syncthreads();
    if (lane < 32) {
        int cnt = 0;
        for (int e = 0; e < 64; ++e) cnt += (dL[wave][e] == lane) ? 1 : 0;
        int incl = cnt;
        #pragma unroll
        for (int d = 1; d < 32; d <<= 1) {
            int v = __shfl_up(incl, d, 64);
            if (lane >= d) incl += v;
        }
        int start = incl - cnt;
        off[sgi * 32 + lane] = (u16)start;
        int pos = start;
        for (int e = 0; e < 64; ++e) {
            if (dL[wave][e] == lane) {
                perm[sgi * 64 + pos] = (u16)((sL[wave][e] << 3) | eL[wave][e]);
                ++pos;
            }
        }
    }
}

// ---------------------------------------------------------------------------
// Weight transpose+convert: W (K x N f32, slice z) -> WT (N x K bf16).
__global__ __launch_bounds__(256) void k_wtrans(
    const float* __restrict__ W, u16* __restrict__ WT, int K, int N)
{
    __shared__ float til[32][33];
    int k0 = blockIdx.x * 32, n0 = blockIdx.y * 32, s = blockIdx.z;
    const float* Wb = W + (size_t)s * K * N;
    u16* Tb = WT + (size_t)s * N * K;
    int j = threadIdx.x & 31, i0 = threadIdx.x >> 5;
    #pragma unroll
    for (int it = 0; it < 4; ++it) {
        int i = i0 + it * 8;
        til[i][j] = Wb[(size_t)(k0 + i) * N + n0 + j];
    }
    __syncthreads();
    #pragma unroll
    for (int it = 0; it < 4; ++it) {
        int i = i0 + it * 8;
        Tb[(size_t)(n0 + i) * K + k0 + j] = f2us(til[j][i]);
    }
}

// ---------------------------------------------------------------------------
// Fully-fused GNN (verified R9 body, spill-fixed launch bounds 256,2).
__global__ __launch_bounds__(256, 2) void k_gnn4(
    const int* __restrict__ x_ids, const int* __restrict__ dist,
    const int* __restrict__ nodes, const float* __restrict__ lp,
    const float* __restrict__ atom_emb, const float* __restrict__ dist_emb,
    const float* __restrict__ logp_W, const float* __restrict__ logp_b,
    const u16* __restrict__ perm, const u16* __restrict__ off,
    const float* __restrict__ bond_emb, const float* __restrict__ eps_arr,
    const float* __restrict__ b1a, const float* __restrict__ b2a,
    const u16* __restrict__ W1T, const u16* __restrict__ W2T,
    float* __restrict__ x)
{
    __shared__ __align__(16) unsigned char smem[38912];
    u16*   hz    = (u16*)smem;
    float* bondL = (float*)(smem + 32768);
    u16*   permL = (u16*)(smem + 32768 + 5120);
    u16*   offL  = (u16*)(smem + 32768 + 5120 + 256);
    float* validL= (float*)(smem + 32768 + 5120 + 512);
    float* epsL  = (float*)(smem + 32768 + 5120 + 512 + 256);

    int tid = threadIdx.x, lane = tid & 63, wave = tid >> 6;
    int row0 = blockIdx.x * 64;
    int fr = lane & 15, quad = lane >> 4;

    for (int i = tid; i < EDN * 256; i += 256) bondL[i] = bond_emb[i];
    if (tid < 128) permL[tid] = perm[blockIdx.x * 128 + tid];
    if (tid < 64) {
        offL[tid] = off[blockIdx.x * 64 + tid];
        validL[tid] = (nodes[row0 + tid] >= 0) ? 1.0f : 0.0f;
    }
    if (tid < 4) epsL[tid] = eps_arr[tid];

    {
        int m = tid & 63, qd = tid >> 6;
        int rg = row0 + m;
        float valid = (nodes[rg] >= 0) ? 1.0f : 0.0f;
        float lpv = finite_or_zero(lp[rg >> 5]);
        int dc = dist[rg]; dc = dc < 0 ? 0 : (dc > MAXD ? MAXD : dc);
        int xid = x_ids[rg];
        #pragma unroll
        for (int k = 0; k < 8; ++k) {
            int cc = qd * 8 + k, c = cc * 8;
            float4 a0 = *reinterpret_cast<const float4*>(atom_emb + xid * 256 + c);
            float4 a1 = *reinterpret_cast<const float4*>(atom_emb + xid * 256 + c + 4);
            float4 d0 = *reinterpret_cast<const float4*>(dist_emb + dc * 256 + c);
            float4 d1 = *reinterpret_cast<const float4*>(dist_emb + dc * 256 + c + 4);
            float4 w0 = *reinterpret_cast<const float4*>(logp_W + c);
            float4 w1 = *reinterpret_cast<const float4*>(logp_W + c + 4);
            float4 p0 = *reinterpret_cast<const float4*>(logp_b + c);
            float4 p1 = *reinterpret_cast<const float4*>(logp_b + c + 4);
            union { bf16x8 v; ushort4 h[2]; } o;
            o.h[0] = (ushort4){
                f2us((a0.x + d0.x + fmaxf(lpv * w0.x + p0.x, 0.f)) * valid),
                f2us((a0.y + d0.y + fmaxf(lpv * w0.y + p0.y, 0.f)) * valid),
                f2us((a0.z + d0.z + fmaxf(lpv * w0.z + p0.z, 0.f)) * valid),
                f2us((a0.w + d0.w + fmaxf(lpv * w0.w + p0.w, 0.f)) * valid) };
            o.h[1] = (ushort4){
                f2us((a1.x + d1.x + fmaxf(lpv * w1.x + p1.x, 0.f)) * valid),
                f2us((a1.y + d1.y + fmaxf(lpv * w1.y + p1.y, 0.f)) * valid),
                f2us((a1.z + d1.z + fmaxf(lpv * w1.z + p1.z, 0.f)) * valid),
                f2us((a1.w + d1.w + fmaxf(lpv * w1.w + p1.w, 0.f)) * valid) };
            *reinterpret_cast<bf16x8*>(hz + m * 256 + ((cc ^ (m & 7)) * 8)) = o.v;
        }
    }
    __syncthreads();

    int rl = tid >> 3, g8 = tid & 7;
    for (int l = 0; l < LLAY; ++l) {
        float ep1 = 1.0f + epsL[l];
        for (int p = 0; p < 2; ++p) {
            int row = p * 32 + rl;
            int e0 = offL[p * 32 + rl];
            int e1 = (rl < 31) ? offL[p * 32 + rl + 1] : 64;
            float a[32];
            #pragma unroll
            for (int q = 0; q < 32; ++q) a[q] = 0.f;
            for (int j = e0; j < e1; ++j) {
                int ent = permL[p * 64 + j];
                int sl = p * 32 + (ent >> 3);
                int be = ent & 7;
                #pragma unroll
                for (int q = 0; q < 4; ++q) {
                    union { bf16x8 v; u16 s[8]; } hv;
                    hv.v = *reinterpret_cast<const bf16x8*>(
                        hz + sl * 256 + (((g8 * 4 + q) ^ (sl & 7)) * 8));
                    const float* bp = bondL + be * 256 + g8 * 32 + q * 8;
                    float4 bo0 = *reinterpret_cast<const float4*>(bp);
                    float4 bo1 = *reinterpret_cast<const float4*>(bp + 4);
                    a[q*8+0] += fmaxf(us2f(hv.s[0]) + bo0.x, 0.f);
                    a[q*8+1] += fmaxf(us2f(hv.s[1]) + bo0.y, 0.f);
                    a[q*8+2] += fmaxf(us2f(hv.s[2]) + bo0.z, 0.f);
                    a[q*8+3] += fmaxf(us2f(hv.s[3]) + bo0.w, 0.f);
                    a[q*8+4] += fmaxf(us2f(hv.s[4]) + bo1.x, 0.f);
                    a[q*8+5] += fmaxf(us2f(hv.s[5]) + bo1.y, 0.f);
                    a[q*8+6] += fmaxf(us2f(hv.s[6]) + bo1.z, 0.f);
                    a[q*8+7] += fmaxf(us2f(hv.s[7]) + bo1.w, 0.f);
                }
            }
            __syncthreads();
            #pragma unroll
            for (int q = 0; q < 4; ++q) {
                u16* ptr = hz + row * 256 + (((g8 * 4 + q) ^ (row & 7)) * 8);
                union { bf16x8 v; u16 s[8]; } hv, ov;
                hv.v = *reinterpret_cast<const bf16x8*>(ptr);
                #pragma unroll
                for (int k = 0; k < 8; ++k)
                    ov.s[k] = f2us(ep1 * us2f(hv.s[k]) + a[q * 8 + k]);
                *reinterpret_cast<bf16x8*>(ptr) = ov.v;
            }
        }
        __syncthreads();

        const u16* W1 = W1T + l * 65536;
        const float* b1 = b1a + l * 256;
        bf16x8 wf[4][8];
        #pragma unroll
        for (int i = 0; i < 4; ++i)
            #pragma unroll
            for (int kc = 0; kc < 8; ++kc)
                wf[i][kc] = *reinterpret_cast<const bf16x8*>(
                    W1 + (size_t)(wave * 64 + i * 16 + fr) * 256 + kc * 32 + quad * 8);
        f32x4 acc[4][4];
        #pragma unroll
        for (int i = 0; i < 4; ++i)
            #pragma unroll
            for (int j = 0; j < 4; ++j) acc[i][j] = (f32x4){0.f, 0.f, 0.f, 0.f};
        #pragma unroll
        for (int kc = 0; kc < 8; ++kc) {
            bf16x8 bfv[4];
            #pragma unroll
            for (int j = 0; j < 4; ++j) {
                int m = j * 16 + fr;
                bfv[j] = *reinterpret_cast<const bf16x8*>(hz + m * 256 + (((kc * 4 + quad) ^ (m & 7)) * 8));
            }
            #pragma unroll
            for (int i = 0; i < 4; ++i)
                #pragma unroll
                for (int j = 0; j < 4; ++j)
                    acc[i][j] = __builtin_amdgcn_mfma_f32_16x16x32_bf16(wf[i][kc], bfv[j], acc[i][j], 0, 0, 0);
        }
        __syncthreads();
        #pragma unroll
        for (int i = 0; i < 4; ++i) {
            int n1b = wave * 64 + i * 16 + quad * 4;
            float4 bb = *reinterpret_cast<const float4*>(b1 + n1b);
            #pragma unroll
            for (int j = 0; j < 4; ++j) {
                int m = j * 16 + fr;
                ushort4 o = { f2us(fmaxf(acc[i][j][0] + bb.x, 0.f)),
                              f2us(fmaxf(acc[i][j][1] + bb.y, 0.f)),
                              f2us(fmaxf(acc[i][j][2] + bb.z, 0.f)),
                              f2us(fmaxf(acc[i][j][3] + bb.w, 0.f)) };
                *reinterpret_cast<ushort4*>(hz + m * 256 + (((n1b >> 3) ^ (m & 7)) * 8) + (n1b & 7)) = o;
            }
        }
        __syncthreads();

        const u16* W2 = W2T + l * 65536;
        const float* b2 = b2a + l * 256;
        #pragma unroll
        for (int i = 0; i < 4; ++i)
            #pragma unroll
            for (int kc = 0; kc < 8; ++kc)
                wf[i][kc] = *reinterpret_cast<const bf16x8*>(
                    W2 + (size_t)(wave * 64 + i * 16 + fr) * 256 + kc * 32 + quad * 8);
        #pragma unroll
        for (int i = 0; i < 4; ++i)
            #pragma unroll
            for (int j = 0; j < 4; ++j) acc[i][j] = (f32x4){0.f, 0.f, 0.f, 0.f};
        #pragma unroll
        for (int kc = 0; kc < 8; ++kc) {
            bf16x8 bfv[4];
            #pragma unroll
            for (int j = 0; j < 4; ++j) {
                int m = j * 16 + fr;
                bfv[j] = *reinterpret_cast<const bf16x8*>(hz + m * 256 + (((kc * 4 + quad) ^ (m & 7)) * 8));
            }
            #pragma unroll
            for (int i = 0; i < 4; ++i)
                #pragma unroll
                for (int j = 0; j < 4; ++j)
                    acc[i][j] = __builtin_amdgcn_mfma_f32_16x16x32_bf16(wf[i][kc], bfv[j], acc[i][j], 0, 0, 0);
        }
        __syncthreads();

        if (l < LLAY - 1) {
            #pragma unroll
            for (int i = 0; i < 4; ++i) {
                int n2b = wave * 64 + i * 16 + quad * 4;
                float4 bb = *reinterpret_cast<const float4*>(b2 + n2b);
                #pragma unroll
                for (int j = 0; j < 4; ++j) {
                    int m = j * 16 + fr;
                    float vm = validL[m];
                    ushort4 o = { f2us((acc[i][j][0] + bb.x) * vm),
                                  f2us((acc[i][j][1] + bb.y) * vm),
                                  f2us((acc[i][j][2] + bb.z) * vm),
                                  f2us((acc[i][j][3] + bb.w) * vm) };
                    *reinterpret_cast<ushort4*>(hz + m * 256 + (((n2b >> 3) ^ (m & 7)) * 8) + (n2b & 7)) = o;
                }
            }
            __syncthreads();
        } else {
            if (fr == 0) {
                #pragma unroll
                for (int i = 0; i < 4; ++i) {
                    int n2b = wave * 64 + i * 16 + quad * 4;
                    float4 bb = *reinterpret_cast<const float4*>(b2 + n2b);
                    #pragma unroll
                    for (int jj = 0; jj < 2; ++jj) {
                        int j = jj * 2, m = j * 16;
                        float vm = validL[m];
                        float4 o = { (acc[i][j][0] + bb.x) * vm,
                                     (acc[i][j][1] + bb.y) * vm,
                                     (acc[i][j][2] + bb.z) * vm,
                                     (acc[i][j][3] + bb.w) * vm };
                        *reinterpret_cast<float4*>(
                            x + (size_t)(blockIdx.x * 2 + (m >> 5)) * 256 + n2b) = o;
                    }
                }
            }
        }
    }
}

// ---------------------------------------------------------------------------
// Overlap bias via 512-bit LDS bitmaps (verified R3 body).
__global__ __launch_bounds__(1024) void k_bias(
    const int* __restrict__ nodes, const float* __restrict__ lp,
    const float* __restrict__ ovl_emb, const float* __restrict__ alpha_p,
    float* __restrict__ bias)
{
    int b = blockIdx.x, tid = threadIdx.x;
    __shared__ int nd[32][32];
    __shared__ unsigned int bmv[32][17];
    __shared__ float lpc[32];
    __shared__ float emb[16];
    nd[tid >> 5][tid & 31] = nodes[b * 1024 + tid];
    if (tid < 512) bmv[tid >> 4][tid & 15] = 0u;
    if (tid < 32) {
        float l = finite_or_zero(lp[b * 32 + tid]);
        l = l < -30.f ? -30.f : (l > 0.f ? 0.f : l);
        lpc[tid] = l;
    }
    if (tid >= 64 && tid < 64 + KMAXC + 1) emb[tid - 64] = ovl_emb[tid - 64];
    __syncthreads();
    int own = nd[tid >> 5][tid & 31];
    if (own >= 0) atomicOr(&bmv[tid >> 5][own >> 5], 1u << (own & 31));
    __syncthreads();
    int i = tid >> 5, j = tid & 31;
    float alpha = alpha_p[0];
    int cnt = 0;
    #pragma unroll
    for (int k = 0; k < 32; ++k) {
        int nk = nd[i][k];
        if (nk >= 0) cnt += (int)((bmv[j][nk >> 5] >> (nk & 31)) & 1u);
    }
    bias[b * 1024 + tid] = emb[cnt > KMAXC ? KMAXC : cnt] - alpha * lpc[j];
}

// ---------------------------------------------------------------------------
// Per-(batch,head) fused LN1 + qkv-slice GEMM + attention. Grid 256.
// q/k/v stay f32 in LDS (better than prior bf16 round-trip). ob bf16 out.
__global__ __launch_bounds__(256, 2) void k_attn_ln(
    const float* __restrict__ x, const float* __restrict__ biasb,
    const float* __restrict__ ln1_g, const float* __restrict__ ln1_b,
    const u16* __restrict__ qkvT, u16* __restrict__ ob)
{
    __shared__ __align__(16) float xf[32 * 260];   // 33280 B
    __shared__ __align__(16) u16 rb[32 * 256];     // 16384
    __shared__ __align__(16) float qs[32 * 68];    // 8704
    __shared__ __align__(16) float ks[32 * 68];
    __shared__ __align__(16) float vs[32 * 68];
    __shared__ float sc[32 * 33];                  // 4224
    int tid = threadIdx.x, lane = tid & 63, wave = tid >> 6;
    int b = blockIdx.x >> 2, h = blockIdx.x & 3;
    int fr = lane & 15, quad = lane >> 4;

    #pragma unroll
    for (int u = 0; u < 8; ++u) {
        int v = u * 256 + tid;
        int i = v >> 6, c = (v & 63) * 4;
        *reinterpret_cast<float4*>(xf + i * 260 + c) =
            *reinterpret_cast<const float4*>(x + (size_t)(b * 32 + i) * 256 + c);
    }
    __syncthreads();
    // LN1 -> rb (bf16, swizzled)
    #pragma unroll
    for (int rr = 0; rr < 8; ++rr) {
        int row = wave * 8 + rr;
        float4 xv = *reinterpret_cast<const float4*>(xf + row * 260 + lane * 4);
        float s = xv.x + xv.y + xv.z + xv.w;
        #pragma unroll
        for (int o2 = 32; o2 > 0; o2 >>= 1) s += __shfl_xor(s, o2);
        float mu = s * (1.0f / 256.0f);
        float d0 = xv.x - mu, d1 = xv.y - mu, d2 = xv.z - mu, d3 = xv.w - mu;
        float sq = d0 * d0 + d1 * d1 + d2 * d2 + d3 * d3;
        #pragma unroll
        for (int o2 = 32; o2 > 0; o2 >>= 1) sq += __shfl_xor(sq, o2);
        float rs = rsqrtf(sq * (1.0f / 256.0f) + 1e-5f);
        int c = lane * 4;
        float4 gv = *reinterpret_cast<const float4*>(ln1_g + c);
        float4 bv = *reinterpret_cast<const float4*>(ln1_b + c);
        ushort4 o = { f2us(d0 * rs * gv.x + bv.x), f2us(d1 * rs * gv.y + bv.y),
                      f2us(d2 * rs * gv.z + bv.z), f2us(d3 * rs * gv.w + bv.w) };
        *reinterpret_cast<ushort4*>(rb + row * 256 + (((c >> 3) ^ (row & 7)) * 8) + (c & 7)) = o;
    }
    __syncthreads();
    // qkv slice: 12 n-tiles (3/wave): nt 0-3 q, 4-7 k, 8-11 v.
    f32x4 acc[3][2];
    #pragma unroll
    for (int i = 0; i < 3; ++i) { acc[i][0] = (f32x4){0,0,0,0}; acc[i][1] = (f32x4){0,0,0,0}; }
    for (int kc = 0; kc < 8; ++kc) {
        bf16x8 wf[3], bfv[2];
        #pragma unroll
        for (int i = 0; i < 3; ++i) {
            int nt = wave * 3 + i;
            int wrow = (nt >> 2) * 256 + h * 64 + (nt & 3) * 16 + fr;
            wf[i] = *reinterpret_cast<const bf16x8*>(qkvT + (size_t)wrow * 256 + kc * 32 + quad * 8);
        }
        #pragma unroll
        for (int j = 0; j < 2; ++j) {
            int m = j * 16 + fr;
            bfv[j] = *reinterpret_cast<const bf16x8*>(rb + m * 256 + (((kc * 4 + quad) ^ (m & 7)) * 8));
        }
        #pragma unroll
        for (int i = 0; i < 3; ++i)
            #pragma unroll
            for (int j = 0; j < 2; ++j)
                acc[i][j] = __builtin_amdgcn_mfma_f32_16x16x32_bf16(wf[i], bfv[j], acc[i][j], 0, 0, 0);
    }
    #pragma unroll
    for (int i = 0; i < 3; ++i) {
        int nt = wave * 3 + i;
        int sec = nt >> 2;
        int nl = (nt & 3) * 16 + quad * 4;
        float* dst = (sec == 0) ? qs : ((sec == 1) ? ks : vs);
        #pragma unroll
        for (int j = 0; j < 2; ++j) {
            int m = j * 16 + fr;
            float4 o = { acc[i][j][0], acc[i][j][1], acc[i][j][2], acc[i][j][3] };
            *reinterpret_cast<float4*>(dst + m * 68 + nl) = o;
        }
    }
    __syncthreads();
    #pragma unroll
    for (int u = 0; u < 4; ++u) {
        int p = tid + u * 256;
        int i = p >> 5, j = p & 31;
        float s = 0.f;
        #pragma unroll
        for (int d = 0; d < 64; ++d) s += qs[i * 68 + d] * ks[j * 68 + d];
        sc[i * 33 + j] = s * 0.125f + biasb[b * 1024 + i * 32 + j];
    }
    __syncthreads();
    if (tid < 32) {
        int i = tid;
        float m = -1e30f;
        for (int j = 0; j < 32; ++j) m = fmaxf(m, sc[i * 33 + j]);
        float sum = 0.f;
        for (int j = 0; j < 32; ++j) { float e = expf(sc[i * 33 + j] - m); sc[i * 33 + j] = e; sum += e; }
        float inv = 1.0f / sum;
        for (int j = 0; j < 32; ++j) sc[i * 33 + j] *= inv;
    }
    __syncthreads();
    #pragma unroll
    for (int u = 0; u < 8; ++u) {
        int idx = tid + u * 256;
        int i = idx >> 6, d = idx & 63;
        float a = 0.f;
        #pragma unroll
        for (int j = 0; j < 32; ++j) a += sc[i * 33 + j] * vs[j * 68 + d];
        ob[(size_t)(b * 32 + i) * 256 + h * 64 + d] = f2us(a);
    }
}

// ---------------------------------------------------------------------------
// Per-16-row-tile fused out-proj+resid + LN2 + f1+gelu + f2+resid. Grid 128.
__global__ __launch_bounds__(256, 2) void k_ffn(
    const u16* __restrict__ ob, float* __restrict__ x,
    const u16* __restrict__ outT, const float* __restrict__ out_b,
    const float* __restrict__ ln2_g, const float* __restrict__ ln2_b,
    const u16* __restrict__ f1T, const float* __restrict__ f1_b,
    const u16* __restrict__ f2T, const float* __restrict__ f2_b)
{
    __shared__ __align__(16) float xf[16 * 260];   // 16640
    __shared__ __align__(16) u16 rb[16 * 256];     // 8192
    __shared__ __align__(16) u16 obL[16 * 256];    // 8192
    __shared__ __align__(16) u16 ffh[16 * 1024];   // 32768
    int tid = threadIdx.x, lane = tid & 63, wave = tid >> 6;
    int row0 = blockIdx.x * 16;
    int fr = lane & 15, quad = lane >> 4;

    #pragma unroll
    for (int u = 0; u < 4; ++u) {
        int v = u * 256 + tid;
        int i = v >> 6, c = (v & 63) * 4;
        *reinterpret_cast<float4*>(xf + i * 260 + c) =
            *reinterpret_cast<const float4*>(x + (size_t)(row0 + i) * 256 + c);
    }
    #pragma unroll
    for (int u = 0; u < 2; ++u) {
        int ch = u * 256 + tid;
        int m = ch >> 5, cc = ch & 31;
        uint4 v = *reinterpret_cast<const uint4*>(ob + (size_t)(row0 + m) * 256 + cc * 8);
        *reinterpret_cast<uint4*>(obL + m * 256 + ((cc ^ (m & 7)) * 8)) = v;
    }
    __syncthreads();

    // out-proj: D[n][m=fr] += resid
    {
        f32x4 acc[4];
        #pragma unroll
        for (int i = 0; i < 4; ++i) acc[i] = (f32x4){0,0,0,0};
        for (int kc = 0; kc < 8; ++kc) {
            bf16x8 bfv = *reinterpret_cast<const bf16x8*>(obL + fr * 256 + (((kc * 4 + quad) ^ (fr & 7)) * 8));
            #pragma unroll
            for (int i = 0; i < 4; ++i) {
                bf16x8 wf = *reinterpret_cast<const bf16x8*>(
                    outT + (size_t)(wave * 64 + i * 16 + fr) * 256 + kc * 32 + quad * 8);
                acc[i] = __builtin_amdgcn_mfma_f32_16x16x32_bf16(wf, bfv, acc[i], 0, 0, 0);
            }
        }
        #pragma unroll
        for (int i = 0; i < 4; ++i) {
            int nb = wave * 64 + i * 16 + quad * 4;
            float4 bv = *reinterpret_cast<const float4*>(out_b + nb);
            float4* px = reinterpret_cast<float4*>(xf + fr * 260 + nb);
            float4 xv = *px;
            xv.x += acc[i][0] + bv.x; xv.y += acc[i][1] + bv.y;
            xv.z += acc[i][2] + bv.z; xv.w += acc[i][3] + bv.w;
            *px = xv;
        }
    }
    __syncthreads();
    // LN2 (4 rows/wave) -> rb swizzled
    #pragma unroll
    for (int rr = 0; rr < 4; ++rr) {
        int row = wave * 4 + rr;
        float4 xv = *reinterpret_cast<const float4*>(xf + row * 260 + lane * 4);
        float s = xv.x + xv.y + xv.z + xv.w;
        #pragma unroll
        for (int o2 = 32; o2 > 0; o2 >>= 1) s += __shfl_xor(s, o2);
        float mu = s * (1.0f / 256.0f);
        float d0 = xv.x - mu, d1 = xv.y - mu, d2 = xv.z - mu, d3 = xv.w - mu;
        float sq = d0 * d0 + d1 * d1 + d2 * d2 + d3 * d3;
        #pragma unroll
        for (int o2 = 32; o2 > 0; o2 >>= 1) sq += __shfl_xor(sq, o2);
        float rs = rsqrtf(sq * (1.0f / 256.0f) + 1e-5f);
        int c = lane * 4;
        float4 gv = *reinterpret_cast<const float4*>(ln2_g + c);
        float4 bv = *reinterpret_cast<const float4*>(ln2_b + c);
        ushort4 o = { f2us(d0 * rs * gv.x + bv.x), f2us(d1 * rs * gv.y + bv.y),
                      f2us(d2 * rs * gv.z + bv.z), f2us(d3 * rs * gv.w + bv.w) };
        *reinterpret_cast<ushort4*>(rb + row * 256 + (((c >> 3) ^ (row & 7)) * 8) + (c & 7)) = o;
    }
    __syncthreads();
    // f1 + gelu -> ffh (16 n-tiles/wave)
    {
        f32x4 acc[16];
        #pragma unroll
        for (int i = 0; i < 16; ++i) acc[i] = (f32x4){0,0,0,0};
        for (int kc = 0; kc < 8; ++kc) {
            bf16x8 bfv = *reinterpret_cast<const bf16x8*>(rb + fr * 256 + (((kc * 4 + quad) ^ (fr & 7)) * 8));
            #pragma unroll
            for (int i = 0; i < 16; ++i) {
                bf16x8 wf = *reinterpret_cast<const bf16x8*>(
                    f1T + (size_t)(wave * 256 + i * 16 + fr) * 256 + kc * 32 + quad * 8);
                acc[i] = __builtin_amdgcn_mfma_f32_16x16x32_bf16(wf, bfv, acc[i], 0, 0, 0);
            }
        }
        #pragma unroll
        for (int i = 0; i < 16; ++i) {
            int nb = wave * 256 + i * 16 + quad * 4;
            float4 bv = *reinterpret_cast<const float4*>(f1_b + nb);
            float v0 = acc[i][0] + bv.x, v1 = acc[i][1] + bv.y;
            float v2 = acc[i][2] + bv.z, v3 = acc[i][3] + bv.w;
            v0 = 0.5f * v0 * (1.0f + erff(v0 * 0.70710678118654752f));
            v1 = 0.5f * v1 * (1.0f + erff(v1 * 0.70710678118654752f));
            v2 = 0.5f * v2 * (1.0f + erff(v2 * 0.70710678118654752f));
            v3 = 0.5f * v3 * (1.0f + erff(v3 * 0.70710678118654752f));
            ushort4 o = { f2us(v0), f2us(v1), f2us(v2), f2us(v3) };
            *reinterpret_cast<ushort4*>(ffh + fr * 1024 + (((nb >> 3) ^ (fr & 7)) * 8) + (nb & 7)) = o;
        }
    }
    __syncthreads();
    // f2 (K=1024) + resid -> xf
    {
        f32x4 acc[4];
        #pragma unroll
        for (int i = 0; i < 4; ++i) acc[i] = (f32x4){0,0,0,0};
        for (int kc = 0; kc < 32; ++kc) {
            bf16x8 bfv = *reinterpret_cast<const bf16x8*>(ffh + fr * 1024 + (((kc * 4 + quad) ^ (fr & 7)) * 8));
            #pragma unroll
            for (int i = 0; i < 4; ++i) {
                bf16x8 wf = *reinterpret_cast<const bf16x8*>(
                    f2T + (size_t)(wave * 64 + i * 16 + fr) * 1024 + kc * 32 + quad * 8);
                acc[i] = __builtin_amdgcn_mfma_f32_16x16x32_bf16(wf, bfv, acc[i], 0, 0, 0);
            }
        }
        #pragma unroll
        for (int i = 0; i < 4; ++i) {
            int nb = wave * 64 + i * 16 + quad * 4;
            float4 bv = *reinterpret_cast<const float4*>(f2_b + nb);
            float4* px = reinterpret_cast<float4*>(xf + fr * 260 + nb);
            float4 xv = *px;
            xv.x += acc[i][0] + bv.x; xv.y += acc[i][1] + bv.y;
            xv.z += acc[i][2] + bv.z; xv.w += acc[i][3] + bv.w;
            *px = xv;
        }
    }
    __syncthreads();
    #pragma unroll
    for (int u = 0; u < 4; ++u) {
        int v = u * 256 + tid;
        int i = v >> 6, c = (v & 63) * 4;
        *reinterpret_cast<float4*>(x + (size_t)(row0 + i) * 256 + c) =
            *reinterpret_cast<const float4*>(xf + i * 260 + c);
    }
}

// ---------------------------------------------------------------------------
// Final LN + softmax(-lp_c)-weighted sum. Grid 64.
__global__ __launch_bounds__(256) void k_fin(
    const float* __restrict__ x, const float* __restrict__ lp,
    const float* __restrict__ lnout_g, const float* __restrict__ lnout_b,
    float* __restrict__ out)
{
    __shared__ __align__(16) float xlnf[32 * 260];
    __shared__ float wfin[32];
    int tid = threadIdx.x, lane = tid & 63, wave = tid >> 6;
    int b = blockIdx.x;
    #pragma unroll
    for (int rr = 0; rr < 8; ++rr) {
        int row = wave * 8 + rr;
        float4 xv = *reinterpret_cast<const float4*>(x + (size_t)(b * 32 + row) * 256 + lane * 4);
        float s = xv.x + xv.y + xv.z + xv.w;
        #pragma unroll
        for (int o2 = 32; o2 > 0; o2 >>= 1) s += __shfl_xor(s, o2);
        float mu = s * (1.0f / 256.0f);
        float d0 = xv.x - mu, d1 = xv.y - mu, d2 = xv.z - mu, d3 = xv.w - mu;
        float sq = d0 * d0 + d1 * d1 + d2 * d2 + d3 * d3;
        #pragma unroll
        for (int o2 = 32; o2 > 0; o2 >>= 1) sq += __shfl_xor(sq, o2);
        float rs = rsqrtf(sq * (1.0f / 256.0f) + 1e-5f);
        int c = lane * 4;
        float4 gv = *reinterpret_cast<const float4*>(lnout_g + c);
        float4 bv = *reinterpret_cast<const float4*>(lnout_b + c);
        float4 o = { d0 * rs * gv.x + bv.x, d1 * rs * gv.y + bv.y,
                     d2 * rs * gv.z + bv.z, d3 * rs * gv.w + bv.w };
        *reinterpret_cast<float4*>(xlnf + row * 260 + c) = o;
    }
    __syncthreads();
    if (tid == 0) {
        float l2[32];
        float m = -1e30f;
        for (int i = 0; i < 32; ++i) {
            float l = finite_or_zero(lp[b * 32 + i]);
            l = l < -30.f ? -30.f : (l > 0.f ? 0.f : l);
            l2[i] = -l;
            m = fmaxf(m, -l);
        }
        float s = 0.f;
        for (int i = 0; i < 32; ++i) { float e = expf(l2[i] - m); wfin[i] = e; s += e; }
        float inv = 1.0f / s;
        for (int i = 0; i < 32; ++i) wfin[i] *= inv;
    }
    __syncthreads();
    float a = 0.f;
    for (int i = 0; i < 32; ++i) a += wfin[i] * xlnf[i * 260 + tid];
    out[(size_t)b * 256 + tid] = a;
}

// ---------------------------------------------------------------------------
extern "C" void kernel_launch(void* const* d_in, const int* in_sizes, int n_in,
                              void* d_out, int out_size, void* d_ws, size_t ws_size,
                              hipStream_t stream)
{
    const int*   x_ids    = (const int*)d_in[0];
    const int*   edge_ids = (const int*)d_in[1];
    const int*   srcp     = (const int*)d_in[2];
    const int*   dstp     = (const int*)d_in[3];
    const int*   nodes    = (const int*)d_in[4];
    const int*   dist     = (const int*)d_in[5];
    const float* lp       = (const float*)d_in[6];
    const float* atom_emb = (const float*)d_in[7];
    const float* bond_emb = (const float*)d_in[8];
    const float* dist_emb = (const float*)d_in[9];
    const float* logp_W   = (const float*)d_in[10];
    const float* logp_b   = (const float*)d_in[11];
    const float* gnn_eps  = (const float*)d_in[12];
    const float* gnn_W1   = (const float*)d_in[13];
    const float* gnn_b1   = (const float*)d_in[14];
    const float* gnn_W2   = (const float*)d_in[15];
    const float* gnn_b2   = (const float*)d_in[16];
    const float* ln1_g    = (const float*)d_in[17];
    const float* ln1_b    = (const float*)d_in[18];
    const float* qkv_W    = (const float*)d_in[19];
    const float* out_W    = (const float*)d_in[20];
    const float* out_b    = (const float*)d_in[21];
    const float* ln2_g    = (const float*)d_in[22];
    const float* ln2_b    = (const float*)d_in[23];
    const float* f1_W     = (const float*)d_in[24];
    const float* f1_b     = (const float*)d_in[25];
    const float* f2_W     = (const float*)d_in[26];
    const float* f2_b     = (const float*)d_in[27];
    const float* lnout_g  = (const float*)d_in[28];
    const float* lnout_b  = (const float*)d_in[29];
    const float* ovl_emb  = (const float*)d_in[30];
    const float* alpha    = (const float*)d_in[31];

    char* ws = (char*)d_ws;
    u16*   gW1T  = (u16*)(ws + 100663296ull);
    u16*   gW2T  = (u16*)(ws + 100663296ull + 524288ull);
    u16*   permW = (u16*)(ws + 100663296ull + 1048576ull);
    u16*   offW  = (u16*)(ws + 100663296ull + 1310720ull);
    u16*   qkvT  = (u16*)(ws + 33554432ull);                 // 1.5 MB
    u16*   outT  = (u16*)(ws + 33554432ull + 1572864ull);    // 512 KB
    u16*   f1T   = (u16*)(ws + 33554432ull + 2097152ull);    // 2 MB
    u16*   f2T   = (u16*)(ws + 33554432ull + 4194304ull);    // 2 MB
    u16*   ob    = (u16*)(ws + 33554432ull + 6291456ull);    // 1 MB
    float* biasb = (float*)(ws + 33554432ull + 7340032ull);  // 256 KB
    float* x     = (float*)(ws + 67108864ull);               // 2 MB f32

    k_csr<<<SSUB / 4, 256, 0, stream>>>(srcp, dstp, edge_ids, permW, offW);
    k_wtrans<<<dim3(8, 8, 4), 256, 0, stream>>>(gnn_W1, gW1T, 256, 256);
    k_wtrans<<<dim3(8, 8, 4), 256, 0, stream>>>(gnn_W2, gW2T, 256, 256);
    k_gnn4<<<NNODE / 64, 256, 0, stream>>>(
        x_ids, dist, nodes, lp, atom_emb, dist_emb, logp_W, logp_b,
        permW, offW, bond_emb, gnn_eps, gnn_b1, gnn_b2, gW1T, gW2T, x);
    k_wtrans<<<dim3(8, 24, 4), 256, 0, stream>>>(qkv_W, qkvT, 256, 768);
    k_wtrans<<<dim3(8, 8, 4), 256, 0, stream>>>(out_W, outT, 256, 256);
    k_wtrans<<<dim3(8, 32, 4), 256, 0, stream>>>(f1_W, f1T, 256, 1024);
    k_wtrans<<<dim3(32, 8, 4), 256, 0, stream>>>(f2_W, f2T, 1024, 256);
    k_bias<<<BATCH, 1024, 0, stream>>>(nodes, lp, ovl_emb, alpha, biasb);
    for (int t = 0; t < TLAY; ++t) {
        k_attn_ln<<<BATCH * NHEAD, 256, 0, stream>>>(
            x, biasb, ln1_g + t * 256, ln1_b + t * 256,
            qkvT + (size_t)t * 768 * 256, ob);
        k_ffn<<<SSUB / 16, 256, 0, stream>>>(
            ob, x, outT + (size_t)t * 65536, out_b + t * 256,
            ln2_g + t * 256, ln2_b + t * 256,
            f1T + (size_t)t * 1024 * 256, f1_b + t * 1024,
            f2T + (size_t)t * 256 * 1024, f2_b + t * 256);
    }
    k_fin<<<BATCH, 256, 0, stream>>>(x, lp, lnout_g, lnout_b, (float*)d_out);
}